// Round 12
// baseline (224.317 us; speedup 1.0000x reference)
//
#include <hip/hip_runtime.h>
#include <cstddef>

#define BATCH   2
#define SEQ     2048
#define DMODEL  1024
#define NH      16
#define HDIM    64
#define WIN     256
#define MTOT    4096

typedef __bf16 bf16;
typedef __attribute__((ext_vector_type(8)))  __bf16 bf16x8;
typedef __attribute__((ext_vector_type(4)))  float  f32x4;
typedef __attribute__((ext_vector_type(16))) float  f32x16;

#define GLOAD_LDS(gp, lp) __builtin_amdgcn_global_load_lds( \
    (const __attribute__((address_space(1))) void*)(gp),    \
    (__attribute__((address_space(3))) void*)(lp), 16, 0, 0)

__device__ __forceinline__ float fast_exp2(float x) {
#if __has_builtin(__builtin_amdgcn_exp2f)
  return __builtin_amdgcn_exp2f(x);
#else
  float r; asm("v_exp_f32 %0, %1" : "=v"(r) : "v"(x)); return r;
#endif
}

__device__ __forceinline__ unsigned int cvtpk_bf16(float lo, float hi) {
  unsigned int r;
  asm("v_cvt_pk_bf16_f32 %0, %1, %2" : "=v"(r) : "v"(lo), "v"(hi));
  return r;
}

// ---------------------------------------------------------------------------
// Merged pre-pass: split x, w1, w2 into bf16 hi/lo in one launch.
// ---------------------------------------------------------------------------
__global__ __launch_bounds__(256)
void cvt_all(const float* __restrict__ x, const float* __restrict__ w1,
             const float* __restrict__ w2, bf16* __restrict__ xh,
             bf16* __restrict__ xl, bf16* __restrict__ w1h,
             bf16* __restrict__ w1l, bf16* __restrict__ w2h,
             bf16* __restrict__ w2l) {
  const int bid = blockIdx.x;
  const float* s; bf16 *hp, *lp; int base;
  if (bid < 2048)      { s = x;  hp = xh;  lp = xl;  base = bid * 2048; }
  else if (bid < 3584) { s = w1; hp = w1h; lp = w1l; base = (bid - 2048) * 2048; }
  else                 { s = w2; hp = w2h; lp = w2l; base = (bid - 3584) * 2048; }
  const int i = base + threadIdx.x * 8;
  float4 a = *(const float4*)(s + i);
  float4 c = *(const float4*)(s + i + 4);
  const float f[8] = {a.x, a.y, a.z, a.w, c.x, c.y, c.z, c.w};
  bf16x8 vh, vl;
#pragma unroll
  for (int j = 0; j < 8; ++j) {
    bf16 hh = (bf16)f[j];
    vh[j] = hh;
    vl[j] = (bf16)(f[j] - (float)hh);
  }
  *(bf16x8*)(hp + i) = vh;
  *(bf16x8*)(lp + i) = vl;
}

// ---------------------------------------------------------------------------
// R19: fused QKV + V^T = R16 + 2-bit LDS XOR swizzle (T2 for 64B rows).
// R18 counters: 5.24M SQ_LDS_BANK_CONFLICT over ~327K ds_read_b128 = ~16
// extra cyc/read. Cause: frag reads at row*64B + quad*16B put even rows
// in banks 0-15, odd in 16-31; a phase's rows {0,2,4,6} at fixed quad hit
// the SAME 4-bank group (4-way). Fix: 16B-slot index ^= (row>>1)&3 —
// rows 0..7 of one phase then cover all 32 banks once. Per rule #21:
// inverse-swizzled GLOBAL source col for global_load_lds (linear dest)
// + same XOR on ds_read. Bit-identical results (index bijection).
// All other R16 structure unchanged (XCD-local panels, 2Q+1K+1V /CU).
//
// Frag-order K tile layout, 8KB per (b,h,kt): base ((b*16+h)*32+kt)*4096,
//   elem (key,d): ((key>>5)*4+(d>>4))*512 + (((d>>3)&1)*32+(key&31))*8 + (d&7)
// V tile elem (key,d): ((d>>5)*4+((key&63)>>4))*512
//                      + (((key>>3)&1)*32+(d&31))*8 + (key&7)
// ---------------------------------------------------------------------------
__global__ __launch_bounds__(256, 4)
void gemm_qkv_fused(const bf16* __restrict__ xh, const bf16* __restrict__ xl,
                    const bf16* __restrict__ w1h, const bf16* __restrict__ w1l,
                    const float* __restrict__ b1,
                    bf16* __restrict__ Qh, bf16* __restrict__ Ql,
                    bf16* __restrict__ Kt, bf16* __restrict__ Vt) {
  __shared__ bf16 sAh[128 * 32];
  __shared__ bf16 sAl[128 * 32];
  __shared__ bf16 sBh[128 * 32];
  __shared__ bf16 sBl[64 * 32];

  const int t = threadIdx.x, w = t >> 6, lane = t & 63;
  const int ln15 = lane & 15, quad = lane >> 4;
  const int drow = lane >> 2;
  // staging source col, pre-swizzled so linear LDS dest = swizzled layout:
  const int dkswz = (((lane & 3) ^ ((drow >> 1) & 3)) * 8);
  // reader col within row: swizzled 16B slot
  const int qswz = ((quad ^ ((ln15 >> 1) & 3)) * 8);
  const int bid = blockIdx.x;

  if (bid < 512) {
    // ---- Q: 128x64 tile, hi/lo cross (3 MFMA). XCD-local panel group.
    const int g = bid & 7, s = bid >> 3;       // g = XCD, s = 0..63
    const int bm = (g * 4 + (s >> 4)) * 128;   // 4 contiguous panels/XCD
    const int bn = (s & 15) * 64;

    f32x4 acc[2][4];
#pragma unroll
    for (int i = 0; i < 2; ++i)
#pragma unroll
      for (int j = 0; j < 4; ++j)
#pragma unroll
        for (int r = 0; r < 4; ++r) acc[i][j][r] = 0.f;

    for (int k0 = 0; k0 < DMODEL; k0 += 32) {
      __syncthreads();
#pragma unroll
      for (int half = 0; half < 2; ++half) {
        const int r = w * 32 + half * 16 + drow;
        const size_t goffA = (size_t)(bm + r) * DMODEL + k0 + dkswz;
        const int loff = (w * 32 + half * 16) * 32;
        GLOAD_LDS(xh + goffA, sAh + loff);
        GLOAD_LDS(xl + goffA, sAl + loff);
      }
      {
        const int r = w * 16 + drow;
        const size_t goffB = (size_t)(bn + r) * DMODEL + k0 + dkswz;
        const int loff = (w * 16) * 32;
        GLOAD_LDS(w1h + goffB, sBh + loff);
        GLOAD_LDS(w1l + goffB, sBl + loff);
      }
      __syncthreads();

      bf16x8 afh[2], afl[2], bfh[4], bfl[4];
#pragma unroll
      for (int mt = 0; mt < 2; ++mt) {
        const int off = (w * 32 + mt * 16 + ln15) * 32 + qswz;
        afh[mt] = *(const bf16x8*)&sAh[off];
        afl[mt] = *(const bf16x8*)&sAl[off];
      }
#pragma unroll
      for (int nt = 0; nt < 4; ++nt) {
        const int off = (nt * 16 + ln15) * 32 + qswz;
        bfh[nt] = *(const bf16x8*)&sBh[off];
        bfl[nt] = *(const bf16x8*)&sBl[off];
      }
#pragma unroll
      for (int mt = 0; mt < 2; ++mt)
#pragma unroll
        for (int nt = 0; nt < 4; ++nt) {
          acc[mt][nt] = __builtin_amdgcn_mfma_f32_16x16x32_bf16(afh[mt], bfh[nt], acc[mt][nt], 0, 0, 0);
          acc[mt][nt] = __builtin_amdgcn_mfma_f32_16x16x32_bf16(afh[mt], bfl[nt], acc[mt][nt], 0, 0, 0);
          acc[mt][nt] = __builtin_amdgcn_mfma_f32_16x16x32_bf16(afl[mt], bfh[nt], acc[mt][nt], 0, 0, 0);
        }
    }

    float bbcol[4];
#pragma unroll
    for (int nt = 0; nt < 4; ++nt) bbcol[nt] = b1[bn + nt * 16 + ln15];

#pragma unroll
    for (int mt = 0; mt < 2; ++mt)
#pragma unroll
      for (int r = 0; r < 4; ++r) {
        const size_t grow = (size_t)(bm + w * 32 + mt * 16 + quad * 4 + r);
#pragma unroll
        for (int nt = 0; nt < 4; ++nt) {
          const int col = bn + nt * 16 + ln15;
          const float v = acc[mt][nt][r] + bbcol[nt];
          const bf16 hh = (bf16)v;
          Qh[grow * 1024 + col] = hh;
          Ql[grow * 1024 + col] = (bf16)(v - (float)hh);
        }
      }
  } else if (bid < 768) {
    // ---- K: 128x128 hh-only -> Kt frag-order tiles. XCD-local panels.
    const int kid = bid - 512;
    const int g = kid & 7, s = kid >> 3;       // g = XCD, s = 0..31
    const int bm = (g * 4 + (s >> 3)) * 128;   // 4 contiguous panels/XCD
    const int bn = 1024 + (s & 7) * 128;
    const int wrow = (w & 1) * 64, wcol = (w >> 1) * 64;

    f32x4 acc[4][4];
#pragma unroll
    for (int i = 0; i < 4; ++i)
#pragma unroll
      for (int j = 0; j < 4; ++j)
#pragma unroll
        for (int r = 0; r < 4; ++r) acc[i][j][r] = 0.f;

    for (int k0 = 0; k0 < DMODEL; k0 += 32) {
      __syncthreads();
#pragma unroll
      for (int half = 0; half < 2; ++half) {
        const int r = w * 32 + half * 16 + drow;
        const int loff = (w * 32 + half * 16) * 32;
        GLOAD_LDS(xh + (size_t)(bm + r) * DMODEL + k0 + dkswz, sAh + loff);
        GLOAD_LDS(w1h + (size_t)(bn + r) * DMODEL + k0 + dkswz, sBh + loff);
      }
      __syncthreads();

      bf16x8 af[4], bf[4];
#pragma unroll
      for (int mt = 0; mt < 4; ++mt)
        af[mt] = *(const bf16x8*)&sAh[(wrow + mt * 16 + ln15) * 32 + qswz];
#pragma unroll
      for (int nt = 0; nt < 4; ++nt)
        bf[nt] = *(const bf16x8*)&sBh[(wcol + nt * 16 + ln15) * 32 + qswz];
#pragma unroll
      for (int mt = 0; mt < 4; ++mt)
#pragma unroll
        for (int nt = 0; nt < 4; ++nt)
          acc[mt][nt] = __builtin_amdgcn_mfma_f32_16x16x32_bf16(af[mt], bf[nt], acc[mt][nt], 0, 0, 0);
    }

    float bbcol[4];
#pragma unroll
    for (int nt = 0; nt < 4; ++nt) bbcol[nt] = b1[bn + wcol + nt * 16 + ln15];

#pragma unroll
    for (int mt = 0; mt < 4; ++mt)
#pragma unroll
      for (int r = 0; r < 4; ++r) {
        const size_t grow = (size_t)(bm + wrow + mt * 16 + quad * 4 + r);
        const int btok = (int)(grow >> 11), key = (int)(grow & 2047);
        const int kt = key >> 6, kw = key & 63;
#pragma unroll
        for (int nt = 0; nt < 4; ++nt) {
          const int col = bn + wcol + nt * 16 + ln15;
          const float v = acc[mt][nt][r] + bbcol[nt];
          const int hh2 = (col - 1024) >> 6, d = col & 63;
          const size_t addr = ((size_t)((btok * 16 + hh2) * 32 + kt) << 12)
                            + (((kw >> 5) * 4 + (d >> 4)) << 9)
                            + ((((d >> 3) & 1) << 5) + (kw & 31)) * 8 + (d & 7);
          Kt[addr] = (bf16)v;
        }
      }
  } else {
    // ---- V^T: A = w1h rows 2048..3071, B = xh, hh-only -> Vt tiles.
    const int vid = bid - 768;
    const int bm = (vid >> 5) * 128, bn = (vid & 31) * 128;
    const int wrow = (w & 1) * 64, wcol = (w >> 1) * 64;
    const bf16* Ah = w1h + 2048 * 1024;
    const float* bias = b1 + 2048;

    f32x4 acc[4][4];
#pragma unroll
    for (int i = 0; i < 4; ++i)
#pragma unroll
      for (int j = 0; j < 4; ++j)
#pragma unroll
        for (int r = 0; r < 4; ++r) acc[i][j][r] = 0.f;

    for (int k0 = 0; k0 < DMODEL; k0 += 32) {
      __syncthreads();
#pragma unroll
      for (int half = 0; half < 2; ++half) {
        const int r = w * 32 + half * 16 + drow;
        const int loff = (w * 32 + half * 16) * 32;
        GLOAD_LDS(Ah + (size_t)(bm + r) * DMODEL + k0 + dkswz, sAh + loff);
        GLOAD_LDS(xh + (size_t)(bn + r) * DMODEL + k0 + dkswz, sBh + loff);
      }
      __syncthreads();

      bf16x8 af[4], bf[4];
#pragma unroll
      for (int mt = 0; mt < 4; ++mt)
        af[mt] = *(const bf16x8*)&sAh[(wrow + mt * 16 + ln15) * 32 + qswz];
#pragma unroll
      for (int nt = 0; nt < 4; ++nt)
        bf[nt] = *(const bf16x8*)&sBh[(wcol + nt * 16 + ln15) * 32 + qswz];
#pragma unroll
      for (int mt = 0; mt < 4; ++mt)
#pragma unroll
        for (int nt = 0; nt < 4; ++nt)
          acc[mt][nt] = __builtin_amdgcn_mfma_f32_16x16x32_bf16(af[mt], bf[nt], acc[mt][nt], 0, 0, 0);
    }

#pragma unroll
    for (int mt = 0; mt < 4; ++mt)
#pragma unroll
      for (int r = 0; r < 4; ++r) {
        const size_t grow = (size_t)(bm + wrow + mt * 16 + quad * 4 + r);
        const float brow = bias[grow];
        const int hh2 = (int)(grow >> 6), d = (int)(grow & 63);
#pragma unroll
        for (int nt = 0; nt < 4; ++nt) {
          const int col = bn + wcol + nt * 16 + ln15;
          const float v = acc[mt][nt][r] + brow;
          const int btok = col >> 11, key = col & 2047;
          const int kt = key >> 6, kw = key & 63;
          const size_t addr = ((size_t)((btok * 16 + hh2) * 32 + kt) << 12)
                            + (((d >> 5) * 4 + (kw >> 4)) << 9)
                            + ((((kw >> 3) & 1) << 5) + (d & 31)) * 8 + (kw & 7);
          Vt[addr] = (bf16)v;
        }
      }
  }
}

// ---------------------------------------------------------------------------
// R19: out-proj 64x64 GEMM, BK=64, with FULL 3-bit slot swizzle. R17's
// row-parity XOR still left 4-way even-row collisions (rows 0,2,4,6 at
// fixed quad share a bank group since 128B rows all start at bank 0).
// Now slot ^= (row&7): the 8 rows of a phase cover all 8 16B-slots ->
// all 32 banks. Inverse-swizzled global source + same XOR on ds_read.
// ---------------------------------------------------------------------------
__global__ __launch_bounds__(256)
void gemm_out64(const bf16* __restrict__ Ah, const bf16* __restrict__ Al,
                const bf16* __restrict__ Bh, const bf16* __restrict__ Bl,
                const float* __restrict__ bias, float* __restrict__ Cf) {
  __shared__ bf16 sAh[64 * 64];
  __shared__ bf16 sAl[64 * 64];
  __shared__ bf16 sBh[64 * 64];
  __shared__ bf16 sBl[64 * 64];

  const int t = threadIdx.x, w = t >> 6, lane = t & 63;
  const int ln15 = lane & 15, quad = lane >> 4;
  const int bid = blockIdx.x;
  const int g = bid & 7, s = bid >> 3;        // g = XCD, s = 0..127
  const int bm = (g * 8 + (s >> 4)) * 64;     // 8 contiguous panels/XCD
  const int bn = (s & 15) * 64;
  const int wrow = (w & 1) * 32, wcol = (w >> 1) * 32;
  const int drow8 = lane >> 3;                // 0..7 == row&7 of staged row
  const int dcol8 = (((lane & 7) ^ drow8) * 8);   // inverse-swizzled source

  f32x4 acc[2][2];
#pragma unroll
  for (int i = 0; i < 2; ++i)
#pragma unroll
    for (int j = 0; j < 2; ++j)
#pragma unroll
      for (int r = 0; r < 4; ++r) acc[i][j][r] = 0.f;

  for (int k0 = 0; k0 < DMODEL; k0 += 64) {
    __syncthreads();
#pragma unroll
    for (int p = 0; p < 2; ++p) {
      const int r = w * 16 + p * 8 + drow8;
      const size_t goffA = (size_t)(bm + r) * DMODEL + k0 + dcol8;
      const size_t goffB = (size_t)(bn + r) * DMODEL + k0 + dcol8;
      const int loff = (w * 16 + p * 8) * 64;
      GLOAD_LDS(Ah + goffA, sAh + loff);
      GLOAD_LDS(Al + goffA, sAl + loff);
      GLOAD_LDS(Bh + goffB, sBh + loff);
      GLOAD_LDS(Bl + goffB, sBl + loff);
    }
    __syncthreads();

#pragma unroll
    for (int ks = 0; ks < 2; ++ks) {
      bf16x8 afh[2], afl[2], bfh[2], bfl[2];
#pragma unroll
      for (int mt = 0; mt < 2; ++mt) {
        const int row = wrow + mt * 16 + ln15;
        const int off = row * 64 + (((ks * 4 + quad) ^ (row & 7)) * 8);
        afh[mt] = *(const bf16x8*)&sAh[off];
        afl[mt] = *(const bf16x8*)&sAl[off];
      }
#pragma unroll
      for (int nt = 0; nt < 2; ++nt) {
        const int row = wcol + nt * 16 + ln15;
        const int off = row * 64 + (((ks * 4 + quad) ^ (row & 7)) * 8);
        bfh[nt] = *(const bf16x8*)&sBh[off];
        bfl[nt] = *(const bf16x8*)&sBl[off];
      }
#pragma unroll
      for (int mt = 0; mt < 2; ++mt)
#pragma unroll
        for (int nt = 0; nt < 2; ++nt) {
          acc[mt][nt] = __builtin_amdgcn_mfma_f32_16x16x32_bf16(afh[mt], bfh[nt], acc[mt][nt], 0, 0, 0);
          acc[mt][nt] = __builtin_amdgcn_mfma_f32_16x16x32_bf16(afh[mt], bfl[nt], acc[mt][nt], 0, 0, 0);
          acc[mt][nt] = __builtin_amdgcn_mfma_f32_16x16x32_bf16(afl[mt], bfh[nt], acc[mt][nt], 0, 0, 0);
        }
    }
  }

  float bbcol[2];
#pragma unroll
  for (int nt = 0; nt < 2; ++nt) bbcol[nt] = bias[bn + wcol + nt * 16 + ln15];

#pragma unroll
  for (int mt = 0; mt < 2; ++mt)
#pragma unroll
    for (int r = 0; r < 4; ++r) {
      const size_t grow = (size_t)(bm + wrow + mt * 16 + quad * 4 + r);
#pragma unroll
      for (int nt = 0; nt < 2; ++nt) {
        const int col = bn + wcol + nt * 16 + ln15;
        Cf[grow * 1024 + col] = acc[mt][nt][r] + bbcol[nt];
      }
    }
}

// ---------------------------------------------------------------------------
// R14/R18 attention (unchanged — verified optimum for this structure).
// Swapped QK^T (mfma(K,Q)) -> P row lane-local; cvt_pk + permlane32_swap
// assemble PV A-fragments in-register; l = scalar f32. Zero LDS.
// ---------------------------------------------------------------------------
__global__ __launch_bounds__(64, 2)
void attn_mfma(const bf16* __restrict__ Qh, const bf16* __restrict__ Ql,
               const bf16* __restrict__ Kt, const bf16* __restrict__ Vt,
               bf16* __restrict__ Omh, bf16* __restrict__ Oml) {
  const int lane = threadIdx.x & 63;
  const int ln31 = lane & 31, half = lane >> 5;
  const int bid = blockIdx.x;
  const int j = bid & 31;
  const int bh = ((j & 7) << 2) | (j >> 3);    // bid%8 == bh>>2 -> XCD group
  const int c  = 63 - (bid >> 5);              // 32-row q chunk, long-first
  const int b = bh >> 4, h = bh & 15;
  const int i0w = c * 32;                      // this wave's first q row
  const int lim = i0w + WIN;                   // allowed: key <= q + WIN

  // ---- Q fragments: hi+lo combined, scaled by log2(e)/8, re-split ----
  bf16x8 qh[4], ql[4];
  {
    const size_t rowQ = (size_t)(b * SEQ + i0w + ln31);
#pragma unroll
    for (int ks = 0; ks < 4; ++ks) {
      bf16x8 vh = *(const bf16x8*)(Qh + rowQ * 1024 + h * 64 + ks * 16 + half * 8);
      bf16x8 vl = *(const bf16x8*)(Ql + rowQ * 1024 + h * 64 + ks * 16 + half * 8);
#pragma unroll
      for (int jj = 0; jj < 8; ++jj) {
        float f = ((float)vh[jj] + (float)vl[jj]) * 0.1803368801111204f;  // log2(e)/8
        bf16 hh = (bf16)f;
        qh[ks][jj] = hh;
        ql[ks][jj] = (bf16)(f - (float)hh);
      }
    }
  }

  f32x16 accO0, accO1;
#pragma unroll
  for (int r = 0; r < 16; ++r) { accO0[r] = 0.f; accO1[r] = 0.f; }
  float lsum = 0.f;

  // per-(b,h) tile bases; each tile is 4096 els, frag-slot ordered
  const bf16* KtBH = Kt + ((size_t)(b * 16 + h) << 17);
  const bf16* VtBH = Vt + ((size_t)(b * 16 + h) << 17);
  const int lane8 = lane * 8;

  const int nkt = min((i0w + 31 + WIN) / 64 + 1, SEQ / 64);

  for (int kt = 0; kt < nkt; ++kt) {
    const bf16* Kb = KtBH + ((size_t)kt << 12);
    const bf16* Vb = VtBH + ((size_t)kt << 12);

    // ---- load all 16 K/V fragments for this tile (1KB bursts, L2-hot).
    bf16x8 kf[8], vf[8];
#pragma unroll
    for (int s = 0; s < 8; ++s) {
      kf[s] = *(const bf16x8*)&Kb[(s << 9) + lane8];
      vf[s] = *(const bf16x8*)&Vb[(s << 9) + lane8];
    }

    // ---- S^T = K Q^T (swapped; Q split hh + hl) ----
    f32x16 S0, S1;
#pragma unroll
    for (int r = 0; r < 16; ++r) { S0[r] = 0.f; S1[r] = 0.f; }
    __builtin_amdgcn_s_setprio(1);
#pragma unroll
    for (int ks = 0; ks < 4; ++ks) {
      S0 = __builtin_amdgcn_mfma_f32_32x32x16_bf16(kf[ks], qh[ks], S0, 0, 0, 0);
      S0 = __builtin_amdgcn_mfma_f32_32x32x16_bf16(kf[ks], ql[ks], S0, 0, 0, 0);
      S1 = __builtin_amdgcn_mfma_f32_32x32x16_bf16(kf[4 + ks], qh[ks], S1, 0, 0, 0);
      S1 = __builtin_amdgcn_mfma_f32_32x32x16_bf16(kf[4 + ks], ql[ks], S1, 0, 0, 0);
    }
    __builtin_amdgcn_s_setprio(0);

    // ---- in-register softmax: p = exp2(s), mask, pack to PV fragments ----
    const int j0 = kt * 64;
    bf16x8 pa[4];
#pragma unroll
    for (int cc = 0; cc < 2; ++cc) {
      f32x16& S = cc ? S1 : S0;
      const int base = j0 + cc * 32 - lim;     // zero if kr + base > ln31
      const bool may = (base + 31 > 0);
#pragma unroll
      for (int r = 0; r < 16; ++r) {
        const int kr = (r & 3) + 8 * (r >> 2) + 4 * half;  // key row in block
        float pv = fast_exp2(S[r]);
        if (may && (kr + base > ln31)) pv = 0.f;
        S[r] = pv;
        lsum += pv;
      }
      unsigned int W0[4], W1[4];
#pragma unroll
      for (int g = 0; g < 4; ++g) {
        W0[g] = cvtpk_bf16(S[4 * g + 0], S[4 * g + 1]);
        W1[g] = cvtpk_bf16(S[4 * g + 2], S[4 * g + 3]);
      }
#pragma unroll
      for (int f = 0; f < 2; ++f) {
        auto s0 = __builtin_amdgcn_permlane32_swap(W0[2 * f], W0[2 * f + 1], false, false);
        auto s1 = __builtin_amdgcn_permlane32_swap(W1[2 * f], W1[2 * f + 1], false, false);
        union { unsigned int w[4]; bf16x8 v; } u;
        u.w[0] = (unsigned int)s0[0];
        u.w[1] = (unsigned int)s1[0];
        u.w[2] = (unsigned int)s0[1];
        u.w[3] = (unsigned int)s1[1];
        pa[cc * 2 + f] = u.v;
      }
    }

    // ---- O += P V (A = in-register P fragments; no LDS, no barrier) ----
    __builtin_amdgcn_s_setprio(1);
#pragma unroll
    for (int ks = 0; ks < 4; ++ks) {
      accO0 = __builtin_amdgcn_mfma_f32_32x32x16_bf16(pa[ks], vf[ks], accO0, 0, 0, 0);
      accO1 = __builtin_amdgcn_mfma_f32_32x32x16_bf16(pa[ks], vf[4 + ks], accO1, 0, 0, 0);
    }
    __builtin_amdgcn_s_setprio(0);
  }

  // ---- epilogue: combine l across halves, O /= l, write Om hi/lo ----
  lsum += __shfl_xor(lsum, 32, 64);            // lane q + partner -> full l[q=ln31]
#pragma unroll
  for (int r = 0; r < 16; ++r) {
    const int rl = (r & 3) + 8 * (r >> 2) + 4 * half;
    const float lv = __shfl(lsum, rl, 64);     // l for O row rl
    const float inv = 1.0f / lv;
    const size_t grow = (size_t)(b * SEQ + i0w + rl);
    const int col0 = h * 64 + ln31;
    const float v0 = accO0[r] * inv;
    const float v1 = accO1[r] * inv;
    const bf16 h0 = (bf16)v0, h1 = (bf16)v1;
    Omh[grow * DMODEL + col0]      = h0;
    Oml[grow * DMODEL + col0]      = (bf16)(v0 - (float)h0);
    Omh[grow * DMODEL + col0 + 32] = h1;
    Oml[grow * DMODEL + col0 + 32] = (bf16)(v1 - (float)h1);
  }
}

// ---------------------------------------------------------------------------
extern "C" void kernel_launch(void* const* d_in, const int* in_sizes, int n_in,
                              void* d_out, int out_size, void* d_ws, size_t ws_size,
                              hipStream_t stream) {
  const float* x  = (const float*)d_in[0];
  const float* w1 = (const float*)d_in[1];
  const float* b1 = (const float*)d_in[2];
  const float* w2 = (const float*)d_in[3];
  const float* b2 = (const float*)d_in[4];
  float* out = (float*)d_out;

  char* ws = (char*)d_ws;
  bf16* Qh   = (bf16*)(ws + 0);          // [4096][1024]
  bf16* Ql   = (bf16*)(ws + 8388608);    // [4096][1024]
  bf16* Kt   = (bf16*)(ws + 16777216);   // frag-order tiles, 8 MB
  bf16* Vt   = (bf16*)(ws + 25165824);   // frag-order tiles, 8 MB
  bf16* xh   = (bf16*)(ws + 33554432);   // [4096][1024]
  bf16* xl   = (bf16*)(ws + 41943040);
  bf16* w1h  = (bf16*)(ws + 50331648);   // [3072][1024]
  bf16* w1l  = (bf16*)(ws + 56623104);
  bf16* w2h  = (bf16*)(ws + 62914560);   // [1024][1024]
  bf16* w2l  = (bf16*)(ws + 65011712);
  bf16* Omh  = xh;                       // reuse (x dead after fused gemm)
  bf16* Oml  = xl;

  cvt_all<<<dim3(4096), 256, 0, stream>>>(x, w1, w2, xh, xl, w1h, w1l, w2h, w2l);

  // fused: Q 128x64 (0..511) + K 128x128 (512..767) + V^T (768..1023),
  // XCD-local panels + bank-conflict-free LDS swizzle
  gemm_qkv_fused<<<dim3(1024), 256, 0, stream>>>(
      xh, xl, w1h, w1l, b1, Qh, Ql, Kt, Vt);

  // 1-wave in-register-softmax attention (R14 exact)
  attn_mfma<<<dim3(2048), 64, 0, stream>>>(Qh, Ql, Kt, Vt, Omh, Oml);

  // out = Om @ w2^T + b2 (fp32), 64x64 tiles, BK=64, 3-bit swizzle
  gemm_out64<<<dim3(1024), 256, 0, stream>>>(
      Omh, Oml, w2h, w2l, b2, out);
}

// Round 13
// 223.507 us; speedup vs baseline: 1.0036x; 1.0036x over previous
//
#include <hip/hip_runtime.h>
#include <cstddef>

#define BATCH   2
#define SEQ     2048
#define DMODEL  1024
#define NH      16
#define HDIM    64
#define WIN     256
#define MTOT    4096

typedef __bf16 bf16;
typedef __attribute__((ext_vector_type(8)))  __bf16 bf16x8;
typedef __attribute__((ext_vector_type(4)))  float  f32x4;
typedef __attribute__((ext_vector_type(16))) float  f32x16;

#define GLOAD_LDS(gp, lp) __builtin_amdgcn_global_load_lds( \
    (const __attribute__((address_space(1))) void*)(gp),    \
    (__attribute__((address_space(3))) void*)(lp), 16, 0, 0)

__device__ __forceinline__ float fast_exp2(float x) {
#if __has_builtin(__builtin_amdgcn_exp2f)
  return __builtin_amdgcn_exp2f(x);
#else
  float r; asm("v_exp_f32 %0, %1" : "=v"(r) : "v"(x)); return r;
#endif
}

__device__ __forceinline__ unsigned int cvtpk_bf16(float lo, float hi) {
  unsigned int r;
  asm("v_cvt_pk_bf16_f32 %0, %1, %2" : "=v"(r) : "v"(lo), "v"(hi));
  return r;
}

// ---------------------------------------------------------------------------
// Merged pre-pass: split x, w1, w2 into bf16 hi/lo in one launch.
// ---------------------------------------------------------------------------
__global__ __launch_bounds__(256)
void cvt_all(const float* __restrict__ x, const float* __restrict__ w1,
             const float* __restrict__ w2, bf16* __restrict__ xh,
             bf16* __restrict__ xl, bf16* __restrict__ w1h,
             bf16* __restrict__ w1l, bf16* __restrict__ w2h,
             bf16* __restrict__ w2l) {
  const int bid = blockIdx.x;
  const float* s; bf16 *hp, *lp; int base;
  if (bid < 2048)      { s = x;  hp = xh;  lp = xl;  base = bid * 2048; }
  else if (bid < 3584) { s = w1; hp = w1h; lp = w1l; base = (bid - 2048) * 2048; }
  else                 { s = w2; hp = w2h; lp = w2l; base = (bid - 3584) * 2048; }
  const int i = base + threadIdx.x * 8;
  float4 a = *(const float4*)(s + i);
  float4 c = *(const float4*)(s + i + 4);
  const float f[8] = {a.x, a.y, a.z, a.w, c.x, c.y, c.z, c.w};
  bf16x8 vh, vl;
#pragma unroll
  for (int j = 0; j < 8; ++j) {
    bf16 hh = (bf16)f[j];
    vh[j] = hh;
    vl[j] = (bf16)(f[j] - (float)hh);
  }
  *(bf16x8*)(hp + i) = vh;
  *(bf16x8*)(lp + i) = vl;
}

// ---------------------------------------------------------------------------
// R20: fused QKV + V^T with STAGE-AHEAD DOUBLE BUFFER (min-2-phase
// template, T3 recipe / m248v2). R19 post-mortem: conflicts 5.24M -> 0
// but dur flat => the limiter is the per-k-step vmcnt(0) drain at the
// barrier (same-step DMAs, ~300-900cyc exposed, 32x/block, all blocks
// in phase). Now: issue step t+1's stage into buf^1 BEFORE computing
// step t; ONE barrier per step — its vmcnt(0) waits on loads that aged
// a full k-step under compute. Hazard-free: buf X is read before the
// iter-t barrier, written after it (iter t+1). LDS 28->56KB => 2
// blocks/CU (8 waves); the dbuf pipelining replaces the lost TLP.
// Swizzle (R19), XCD-local panels (R16), per-CU type mix unchanged.
// Bit-identical math.
//
// Frag-order K tile layout, 8KB per (b,h,kt): base ((b*16+h)*32+kt)*4096,
//   elem (key,d): ((key>>5)*4+(d>>4))*512 + (((d>>3)&1)*32+(key&31))*8 + (d&7)
// V tile elem (key,d): ((d>>5)*4+((key&63)>>4))*512
//                      + (((key>>3)&1)*32+(d&31))*8 + (key&7)
// ---------------------------------------------------------------------------
__global__ __launch_bounds__(256, 2)
void gemm_qkv_fused(const bf16* __restrict__ xh, const bf16* __restrict__ xl,
                    const bf16* __restrict__ w1h, const bf16* __restrict__ w1l,
                    const float* __restrict__ b1,
                    bf16* __restrict__ Qh, bf16* __restrict__ Ql,
                    bf16* __restrict__ Kt, bf16* __restrict__ Vt) {
  __shared__ bf16 sAh[2][128 * 32];
  __shared__ bf16 sAl[2][128 * 32];
  __shared__ bf16 sBh[2][128 * 32];
  __shared__ bf16 sBl[2][64 * 32];

  const int t = threadIdx.x, w = t >> 6, lane = t & 63;
  const int ln15 = lane & 15, quad = lane >> 4;
  const int drow = lane >> 2;
  // staging source col, pre-swizzled so linear LDS dest = swizzled layout:
  const int dkswz = (((lane & 3) ^ ((drow >> 1) & 3)) * 8);
  // reader col within row: swizzled 16B slot
  const int qswz = ((quad ^ ((ln15 >> 1) & 3)) * 8);
  const int bid = blockIdx.x;

  if (bid < 512) {
    // ---- Q: 128x64 tile, hi/lo cross (3 MFMA). XCD-local panel group.
    const int g = bid & 7, s = bid >> 3;       // g = XCD, s = 0..63
    const int bm = (g * 4 + (s >> 4)) * 128;   // 4 contiguous panels/XCD
    const int bn = (s & 15) * 64;

    f32x4 acc[2][4];
#pragma unroll
    for (int i = 0; i < 2; ++i)
#pragma unroll
      for (int j = 0; j < 4; ++j)
#pragma unroll
        for (int r = 0; r < 4; ++r) acc[i][j][r] = 0.f;

    // prologue: stage k0=0 into buf 0
#pragma unroll
    for (int half = 0; half < 2; ++half) {
      const int r = w * 32 + half * 16 + drow;
      const size_t goffA = (size_t)(bm + r) * DMODEL + dkswz;
      const int loff = (w * 32 + half * 16) * 32;
      GLOAD_LDS(xh + goffA, &sAh[0][loff]);
      GLOAD_LDS(xl + goffA, &sAl[0][loff]);
    }
    {
      const int r = w * 16 + drow;
      const size_t goffB = (size_t)(bn + r) * DMODEL + dkswz;
      const int loff = (w * 16) * 32;
      GLOAD_LDS(w1h + goffB, &sBh[0][loff]);
      GLOAD_LDS(w1l + goffB, &sBl[0][loff]);
    }
    __syncthreads();

    for (int k0 = 0; k0 < DMODEL; k0 += 32) {
      const int cur = (k0 >> 5) & 1;
      if (k0 + 32 < DMODEL) {
        const int nxt = cur ^ 1;
#pragma unroll
        for (int half = 0; half < 2; ++half) {
          const int r = w * 32 + half * 16 + drow;
          const size_t goffA = (size_t)(bm + r) * DMODEL + (k0 + 32) + dkswz;
          const int loff = (w * 32 + half * 16) * 32;
          GLOAD_LDS(xh + goffA, &sAh[nxt][loff]);
          GLOAD_LDS(xl + goffA, &sAl[nxt][loff]);
        }
        {
          const int r = w * 16 + drow;
          const size_t goffB = (size_t)(bn + r) * DMODEL + (k0 + 32) + dkswz;
          const int loff = (w * 16) * 32;
          GLOAD_LDS(w1h + goffB, &sBh[nxt][loff]);
          GLOAD_LDS(w1l + goffB, &sBl[nxt][loff]);
        }
      }

      bf16x8 afh[2], afl[2], bfh[4], bfl[4];
#pragma unroll
      for (int mt = 0; mt < 2; ++mt) {
        const int off = (w * 32 + mt * 16 + ln15) * 32 + qswz;
        afh[mt] = *(const bf16x8*)&sAh[cur][off];
        afl[mt] = *(const bf16x8*)&sAl[cur][off];
      }
#pragma unroll
      for (int nt = 0; nt < 4; ++nt) {
        const int off = (nt * 16 + ln15) * 32 + qswz;
        bfh[nt] = *(const bf16x8*)&sBh[cur][off];
        bfl[nt] = *(const bf16x8*)&sBl[cur][off];
      }
#pragma unroll
      for (int mt = 0; mt < 2; ++mt)
#pragma unroll
        for (int nt = 0; nt < 4; ++nt) {
          acc[mt][nt] = __builtin_amdgcn_mfma_f32_16x16x32_bf16(afh[mt], bfh[nt], acc[mt][nt], 0, 0, 0);
          acc[mt][nt] = __builtin_amdgcn_mfma_f32_16x16x32_bf16(afh[mt], bfl[nt], acc[mt][nt], 0, 0, 0);
          acc[mt][nt] = __builtin_amdgcn_mfma_f32_16x16x32_bf16(afl[mt], bfh[nt], acc[mt][nt], 0, 0, 0);
        }
      __syncthreads();   // drains next-step DMAs (aged a full k-step)
    }

    float bbcol[4];
#pragma unroll
    for (int nt = 0; nt < 4; ++nt) bbcol[nt] = b1[bn + nt * 16 + ln15];

#pragma unroll
    for (int mt = 0; mt < 2; ++mt)
#pragma unroll
      for (int r = 0; r < 4; ++r) {
        const size_t grow = (size_t)(bm + w * 32 + mt * 16 + quad * 4 + r);
#pragma unroll
        for (int nt = 0; nt < 4; ++nt) {
          const int col = bn + nt * 16 + ln15;
          const float v = acc[mt][nt][r] + bbcol[nt];
          const bf16 hh = (bf16)v;
          Qh[grow * 1024 + col] = hh;
          Ql[grow * 1024 + col] = (bf16)(v - (float)hh);
        }
      }
  } else if (bid < 768) {
    // ---- K: 128x128 hh-only -> Kt frag-order tiles. XCD-local panels.
    const int kid = bid - 512;
    const int g = kid & 7, s = kid >> 3;       // g = XCD, s = 0..31
    const int bm = (g * 4 + (s >> 3)) * 128;   // 4 contiguous panels/XCD
    const int bn = 1024 + (s & 7) * 128;
    const int wrow = (w & 1) * 64, wcol = (w >> 1) * 64;

    f32x4 acc[4][4];
#pragma unroll
    for (int i = 0; i < 4; ++i)
#pragma unroll
      for (int j = 0; j < 4; ++j)
#pragma unroll
        for (int r = 0; r < 4; ++r) acc[i][j][r] = 0.f;

    // prologue: stage k0=0 into buf 0
#pragma unroll
    for (int half = 0; half < 2; ++half) {
      const int r = w * 32 + half * 16 + drow;
      const int loff = (w * 32 + half * 16) * 32;
      GLOAD_LDS(xh + (size_t)(bm + r) * DMODEL + dkswz, &sAh[0][loff]);
      GLOAD_LDS(w1h + (size_t)(bn + r) * DMODEL + dkswz, &sBh[0][loff]);
    }
    __syncthreads();

    for (int k0 = 0; k0 < DMODEL; k0 += 32) {
      const int cur = (k0 >> 5) & 1;
      if (k0 + 32 < DMODEL) {
        const int nxt = cur ^ 1;
#pragma unroll
        for (int half = 0; half < 2; ++half) {
          const int r = w * 32 + half * 16 + drow;
          const int loff = (w * 32 + half * 16) * 32;
          GLOAD_LDS(xh + (size_t)(bm + r) * DMODEL + (k0 + 32) + dkswz, &sAh[nxt][loff]);
          GLOAD_LDS(w1h + (size_t)(bn + r) * DMODEL + (k0 + 32) + dkswz, &sBh[nxt][loff]);
        }
      }

      bf16x8 af[4], bf[4];
#pragma unroll
      for (int mt = 0; mt < 4; ++mt)
        af[mt] = *(const bf16x8*)&sAh[cur][(wrow + mt * 16 + ln15) * 32 + qswz];
#pragma unroll
      for (int nt = 0; nt < 4; ++nt)
        bf[nt] = *(const bf16x8*)&sBh[cur][(wcol + nt * 16 + ln15) * 32 + qswz];
#pragma unroll
      for (int mt = 0; mt < 4; ++mt)
#pragma unroll
        for (int nt = 0; nt < 4; ++nt)
          acc[mt][nt] = __builtin_amdgcn_mfma_f32_16x16x32_bf16(af[mt], bf[nt], acc[mt][nt], 0, 0, 0);
      __syncthreads();
    }

    float bbcol[4];
#pragma unroll
    for (int nt = 0; nt < 4; ++nt) bbcol[nt] = b1[bn + wcol + nt * 16 + ln15];

#pragma unroll
    for (int mt = 0; mt < 4; ++mt)
#pragma unroll
      for (int r = 0; r < 4; ++r) {
        const size_t grow = (size_t)(bm + wrow + mt * 16 + quad * 4 + r);
        const int btok = (int)(grow >> 11), key = (int)(grow & 2047);
        const int kt = key >> 6, kw = key & 63;
#pragma unroll
        for (int nt = 0; nt < 4; ++nt) {
          const int col = bn + wcol + nt * 16 + ln15;
          const float v = acc[mt][nt][r] + bbcol[nt];
          const int hh2 = (col - 1024) >> 6, d = col & 63;
          const size_t addr = ((size_t)((btok * 16 + hh2) * 32 + kt) << 12)
                            + (((kw >> 5) * 4 + (d >> 4)) << 9)
                            + ((((d >> 3) & 1) << 5) + (kw & 31)) * 8 + (d & 7);
          Kt[addr] = (bf16)v;
        }
      }
  } else {
    // ---- V^T: A = w1h rows 2048..3071, B = xh, hh-only -> Vt tiles.
    const int vid = bid - 768;
    const int bm = (vid >> 5) * 128, bn = (vid & 31) * 128;
    const int wrow = (w & 1) * 64, wcol = (w >> 1) * 64;
    const bf16* Ah = w1h + 2048 * 1024;
    const float* bias = b1 + 2048;

    f32x4 acc[4][4];
#pragma unroll
    for (int i = 0; i < 4; ++i)
#pragma unroll
      for (int j = 0; j < 4; ++j)
#pragma unroll
        for (int r = 0; r < 4; ++r) acc[i][j][r] = 0.f;

    // prologue: stage k0=0 into buf 0
#pragma unroll
    for (int half = 0; half < 2; ++half) {
      const int r = w * 32 + half * 16 + drow;
      const int loff = (w * 32 + half * 16) * 32;
      GLOAD_LDS(Ah + (size_t)(bm + r) * DMODEL + dkswz, &sAh[0][loff]);
      GLOAD_LDS(xh + (size_t)(bn + r) * DMODEL + dkswz, &sBh[0][loff]);
    }
    __syncthreads();

    for (int k0 = 0; k0 < DMODEL; k0 += 32) {
      const int cur = (k0 >> 5) & 1;
      if (k0 + 32 < DMODEL) {
        const int nxt = cur ^ 1;
#pragma unroll
        for (int half = 0; half < 2; ++half) {
          const int r = w * 32 + half * 16 + drow;
          const int loff = (w * 32 + half * 16) * 32;
          GLOAD_LDS(Ah + (size_t)(bm + r) * DMODEL + (k0 + 32) + dkswz, &sAh[nxt][loff]);
          GLOAD_LDS(xh + (size_t)(bn + r) * DMODEL + (k0 + 32) + dkswz, &sBh[nxt][loff]);
        }
      }

      bf16x8 af[4], bf[4];
#pragma unroll
      for (int mt = 0; mt < 4; ++mt)
        af[mt] = *(const bf16x8*)&sAh[cur][(wrow + mt * 16 + ln15) * 32 + qswz];
#pragma unroll
      for (int nt = 0; nt < 4; ++nt)
        bf[nt] = *(const bf16x8*)&sBh[cur][(wcol + nt * 16 + ln15) * 32 + qswz];
#pragma unroll
      for (int mt = 0; mt < 4; ++mt)
#pragma unroll
        for (int nt = 0; nt < 4; ++nt)
          acc[mt][nt] = __builtin_amdgcn_mfma_f32_16x16x32_bf16(af[mt], bf[nt], acc[mt][nt], 0, 0, 0);
      __syncthreads();
    }

#pragma unroll
    for (int mt = 0; mt < 4; ++mt)
#pragma unroll
      for (int r = 0; r < 4; ++r) {
        const size_t grow = (size_t)(bm + wrow + mt * 16 + quad * 4 + r);
        const float brow = bias[grow];
        const int hh2 = (int)(grow >> 6), d = (int)(grow & 63);
#pragma unroll
        for (int nt = 0; nt < 4; ++nt) {
          const int col = bn + wcol + nt * 16 + ln15;
          const float v = acc[mt][nt][r] + brow;
          const int btok = col >> 11, key = col & 2047;
          const int kt = key >> 6, kw = key & 63;
          const size_t addr = ((size_t)((btok * 16 + hh2) * 32 + kt) << 12)
                            + (((d >> 5) * 4 + (kw >> 4)) << 9)
                            + ((((kw >> 3) & 1) << 5) + (d & 31)) * 8 + (kw & 7);
          Vt[addr] = (bf16)v;
        }
      }
  }
}

// ---------------------------------------------------------------------------
// R19 out-proj (unchanged): 64x64 GEMM, BK=64, 3-bit slot swizzle,
// XCD-local 1D grid, plain stores.
// ---------------------------------------------------------------------------
__global__ __launch_bounds__(256)
void gemm_out64(const bf16* __restrict__ Ah, const bf16* __restrict__ Al,
                const bf16* __restrict__ Bh, const bf16* __restrict__ Bl,
                const float* __restrict__ bias, float* __restrict__ Cf) {
  __shared__ bf16 sAh[64 * 64];
  __shared__ bf16 sAl[64 * 64];
  __shared__ bf16 sBh[64 * 64];
  __shared__ bf16 sBl[64 * 64];

  const int t = threadIdx.x, w = t >> 6, lane = t & 63;
  const int ln15 = lane & 15, quad = lane >> 4;
  const int bid = blockIdx.x;
  const int g = bid & 7, s = bid >> 3;        // g = XCD, s = 0..127
  const int bm = (g * 8 + (s >> 4)) * 64;     // 8 contiguous panels/XCD
  const int bn = (s & 15) * 64;
  const int wrow = (w & 1) * 32, wcol = (w >> 1) * 32;
  const int drow8 = lane >> 3;                // 0..7 == row&7 of staged row
  const int dcol8 = (((lane & 7) ^ drow8) * 8);   // inverse-swizzled source

  f32x4 acc[2][2];
#pragma unroll
  for (int i = 0; i < 2; ++i)
#pragma unroll
    for (int j = 0; j < 2; ++j)
#pragma unroll
      for (int r = 0; r < 4; ++r) acc[i][j][r] = 0.f;

  for (int k0 = 0; k0 < DMODEL; k0 += 64) {
    __syncthreads();
#pragma unroll
    for (int p = 0; p < 2; ++p) {
      const int r = w * 16 + p * 8 + drow8;
      const size_t goffA = (size_t)(bm + r) * DMODEL + k0 + dcol8;
      const size_t goffB = (size_t)(bn + r) * DMODEL + k0 + dcol8;
      const int loff = (w * 16 + p * 8) * 64;
      GLOAD_LDS(Ah + goffA, sAh + loff);
      GLOAD_LDS(Al + goffA, sAl + loff);
      GLOAD_LDS(Bh + goffB, sBh + loff);
      GLOAD_LDS(Bl + goffB, sBl + loff);
    }
    __syncthreads();

#pragma unroll
    for (int ks = 0; ks < 2; ++ks) {
      bf16x8 afh[2], afl[2], bfh[2], bfl[2];
#pragma unroll
      for (int mt = 0; mt < 2; ++mt) {
        const int row = wrow + mt * 16 + ln15;
        const int off = row * 64 + (((ks * 4 + quad) ^ (row & 7)) * 8);
        afh[mt] = *(const bf16x8*)&sAh[off];
        afl[mt] = *(const bf16x8*)&sAl[off];
      }
#pragma unroll
      for (int nt = 0; nt < 2; ++nt) {
        const int row = wcol + nt * 16 + ln15;
        const int off = row * 64 + (((ks * 4 + quad) ^ (row & 7)) * 8);
        bfh[nt] = *(const bf16x8*)&sBh[off];
        bfl[nt] = *(const bf16x8*)&sBl[off];
      }
#pragma unroll
      for (int mt = 0; mt < 2; ++mt)
#pragma unroll
        for (int nt = 0; nt < 2; ++nt) {
          acc[mt][nt] = __builtin_amdgcn_mfma_f32_16x16x32_bf16(afh[mt], bfh[nt], acc[mt][nt], 0, 0, 0);
          acc[mt][nt] = __builtin_amdgcn_mfma_f32_16x16x32_bf16(afh[mt], bfl[nt], acc[mt][nt], 0, 0, 0);
          acc[mt][nt] = __builtin_amdgcn_mfma_f32_16x16x32_bf16(afl[mt], bfh[nt], acc[mt][nt], 0, 0, 0);
        }
    }
  }

  float bbcol[2];
#pragma unroll
  for (int nt = 0; nt < 2; ++nt) bbcol[nt] = bias[bn + wcol + nt * 16 + ln15];

#pragma unroll
  for (int mt = 0; mt < 2; ++mt)
#pragma unroll
    for (int r = 0; r < 4; ++r) {
      const size_t grow = (size_t)(bm + wrow + mt * 16 + quad * 4 + r);
#pragma unroll
      for (int nt = 0; nt < 2; ++nt) {
        const int col = bn + wcol + nt * 16 + ln15;
        Cf[grow * 1024 + col] = acc[mt][nt][r] + bbcol[nt];
      }
    }
}

// ---------------------------------------------------------------------------
// R14/R18 attention (unchanged — verified optimum for this structure).
// Swapped QK^T (mfma(K,Q)) -> P row lane-local; cvt_pk + permlane32_swap
// assemble PV A-fragments in-register; l = scalar f32. Zero LDS.
// ---------------------------------------------------------------------------
__global__ __launch_bounds__(64, 2)
void attn_mfma(const bf16* __restrict__ Qh, const bf16* __restrict__ Ql,
               const bf16* __restrict__ Kt, const bf16* __restrict__ Vt,
               bf16* __restrict__ Omh, bf16* __restrict__ Oml) {
  const int lane = threadIdx.x & 63;
  const int ln31 = lane & 31, half = lane >> 5;
  const int bid = blockIdx.x;
  const int j = bid & 31;
  const int bh = ((j & 7) << 2) | (j >> 3);    // bid%8 == bh>>2 -> XCD group
  const int c  = 63 - (bid >> 5);              // 32-row q chunk, long-first
  const int b = bh >> 4, h = bh & 15;
  const int i0w = c * 32;                      // this wave's first q row
  const int lim = i0w + WIN;                   // allowed: key <= q + WIN

  // ---- Q fragments: hi+lo combined, scaled by log2(e)/8, re-split ----
  bf16x8 qh[4], ql[4];
  {
    const size_t rowQ = (size_t)(b * SEQ + i0w + ln31);
#pragma unroll
    for (int ks = 0; ks < 4; ++ks) {
      bf16x8 vh = *(const bf16x8*)(Qh + rowQ * 1024 + h * 64 + ks * 16 + half * 8);
      bf16x8 vl = *(const bf16x8*)(Ql + rowQ * 1024 + h * 64 + ks * 16 + half * 8);
#pragma unroll
      for (int jj = 0; jj < 8; ++jj) {
        float f = ((float)vh[jj] + (float)vl[jj]) * 0.1803368801111204f;  // log2(e)/8
        bf16 hh = (bf16)f;
        qh[ks][jj] = hh;
        ql[ks][jj] = (bf16)(f - (float)hh);
      }
    }
  }

  f32x16 accO0, accO1;
#pragma unroll
  for (int r = 0; r < 16; ++r) { accO0[r] = 0.f; accO1[r] = 0.f; }
  float lsum = 0.f;

  // per-(b,h) tile bases; each tile is 4096 els, frag-slot ordered
  const bf16* KtBH = Kt + ((size_t)(b * 16 + h) << 17);
  const bf16* VtBH = Vt + ((size_t)(b * 16 + h) << 17);
  const int lane8 = lane * 8;

  const int nkt = min((i0w + 31 + WIN) / 64 + 1, SEQ / 64);

  for (int kt = 0; kt < nkt; ++kt) {
    const bf16* Kb = KtBH + ((size_t)kt << 12);
    const bf16* Vb = VtBH + ((size_t)kt << 12);

    // ---- load all 16 K/V fragments for this tile (1KB bursts, L2-hot).
    bf16x8 kf[8], vf[8];
#pragma unroll
    for (int s = 0; s < 8; ++s) {
      kf[s] = *(const bf16x8*)&Kb[(s << 9) + lane8];
      vf[s] = *(const bf16x8*)&Vb[(s << 9) + lane8];
    }

    // ---- S^T = K Q^T (swapped; Q split hh + hl) ----
    f32x16 S0, S1;
#pragma unroll
    for (int r = 0; r < 16; ++r) { S0[r] = 0.f; S1[r] = 0.f; }
    __builtin_amdgcn_s_setprio(1);
#pragma unroll
    for (int ks = 0; ks < 4; ++ks) {
      S0 = __builtin_amdgcn_mfma_f32_32x32x16_bf16(kf[ks], qh[ks], S0, 0, 0, 0);
      S0 = __builtin_amdgcn_mfma_f32_32x32x16_bf16(kf[ks], ql[ks], S0, 0, 0, 0);
      S1 = __builtin_amdgcn_mfma_f32_32x32x16_bf16(kf[4 + ks], qh[ks], S1, 0, 0, 0);
      S1 = __builtin_amdgcn_mfma_f32_32x32x16_bf16(kf[4 + ks], ql[ks], S1, 0, 0, 0);
    }
    __builtin_amdgcn_s_setprio(0);

    // ---- in-register softmax: p = exp2(s), mask, pack to PV fragments ----
    const int j0 = kt * 64;
    bf16x8 pa[4];
#pragma unroll
    for (int cc = 0; cc < 2; ++cc) {
      f32x16& S = cc ? S1 : S0;
      const int base = j0 + cc * 32 - lim;     // zero if kr + base > ln31
      const bool may = (base + 31 > 0);
#pragma unroll
      for (int r = 0; r < 16; ++r) {
        const int kr = (r & 3) + 8 * (r >> 2) + 4 * half;  // key row in block
        float pv = fast_exp2(S[r]);
        if (may && (kr + base > ln31)) pv = 0.f;
        S[r] = pv;
        lsum += pv;
      }
      unsigned int W0[4], W1[4];
#pragma unroll
      for (int g = 0; g < 4; ++g) {
        W0[g] = cvtpk_bf16(S[4 * g + 0], S[4 * g + 1]);
        W1[g] = cvtpk_bf16(S[4 * g + 2], S[4 * g + 3]);
      }
#pragma unroll
      for (int f = 0; f < 2; ++f) {
        auto s0 = __builtin_amdgcn_permlane32_swap(W0[2 * f], W0[2 * f + 1], false, false);
        auto s1 = __builtin_amdgcn_permlane32_swap(W1[2 * f], W1[2 * f + 1], false, false);
        union { unsigned int w[4]; bf16x8 v; } u;
        u.w[0] = (unsigned int)s0[0];
        u.w[1] = (unsigned int)s1[0];
        u.w[2] = (unsigned int)s0[1];
        u.w[3] = (unsigned int)s1[1];
        pa[cc * 2 + f] = u.v;
      }
    }

    // ---- O += P V (A = in-register P fragments; no LDS, no barrier) ----
    __builtin_amdgcn_s_setprio(1);
#pragma unroll
    for (int ks = 0; ks < 4; ++ks) {
      accO0 = __builtin_amdgcn_mfma_f32_32x32x16_bf16(pa[ks], vf[ks], accO0, 0, 0, 0);
      accO1 = __builtin_amdgcn_mfma_f32_32x32x16_bf16(pa[ks], vf[4 + ks], accO1, 0, 0, 0);
    }
    __builtin_amdgcn_s_setprio(0);
  }

  // ---- epilogue: combine l across halves, O /= l, write Om hi/lo ----
  lsum += __shfl_xor(lsum, 32, 64);            // lane q + partner -> full l[q=ln31]
#pragma unroll
  for (int r = 0; r < 16; ++r) {
    const int rl = (r & 3) + 8 * (r >> 2) + 4 * half;
    const float lv = __shfl(lsum, rl, 64);     // l for O row rl
    const float inv = 1.0f / lv;
    const size_t grow = (size_t)(b * SEQ + i0w + rl);
    const int col0 = h * 64 + ln31;
    const float v0 = accO0[r] * inv;
    const float v1 = accO1[r] * inv;
    const bf16 h0 = (bf16)v0, h1 = (bf16)v1;
    Omh[grow * DMODEL + col0]      = h0;
    Oml[grow * DMODEL + col0]      = (bf16)(v0 - (float)h0);
    Omh[grow * DMODEL + col0 + 32] = h1;
    Oml[grow * DMODEL + col0 + 32] = (bf16)(v1 - (float)h1);
  }
}

// ---------------------------------------------------------------------------
extern "C" void kernel_launch(void* const* d_in, const int* in_sizes, int n_in,
                              void* d_out, int out_size, void* d_ws, size_t ws_size,
                              hipStream_t stream) {
  const float* x  = (const float*)d_in[0];
  const float* w1 = (const float*)d_in[1];
  const float* b1 = (const float*)d_in[2];
  const float* w2 = (const float*)d_in[3];
  const float* b2 = (const float*)d_in[4];
  float* out = (float*)d_out;

  char* ws = (char*)d_ws;
  bf16* Qh   = (bf16*)(ws + 0);          // [4096][1024]
  bf16* Ql   = (bf16*)(ws + 8388608);    // [4096][1024]
  bf16* Kt   = (bf16*)(ws + 16777216);   // frag-order tiles, 8 MB
  bf16* Vt   = (bf16*)(ws + 25165824);   // frag-order tiles, 8 MB
  bf16* xh   = (bf16*)(ws + 33554432);   // [4096][1024]
  bf16* xl   = (bf16*)(ws + 41943040);
  bf16* w1h  = (bf16*)(ws + 50331648);   // [3072][1024]
  bf16* w1l  = (bf16*)(ws + 56623104);
  bf16* w2h  = (bf16*)(ws + 62914560);   // [1024][1024]
  bf16* w2l  = (bf16*)(ws + 65011712);
  bf16* Omh  = xh;                       // reuse (x dead after fused gemm)
  bf16* Oml  = xl;

  cvt_all<<<dim3(4096), 256, 0, stream>>>(x, w1, w2, xh, xl, w1h, w1l, w2h, w2l);

  // fused: Q 128x64 (0..511) + K 128x128 (512..767) + V^T (768..1023),
  // XCD-local panels + swizzle + stage-ahead double buffer
  gemm_qkv_fused<<<dim3(1024), 256, 0, stream>>>(
      xh, xl, w1h, w1l, b1, Qh, Ql, Kt, Vt);

  // 1-wave in-register-softmax attention (R14 exact)
  attn_mfma<<<dim3(2048), 64, 0, stream>>>(Qh, Ql, Kt, Vt, Omh, Oml);

  // out = Om @ w2^T + b2 (fp32), 64x64 tiles, BK=64, 3-bit swizzle
  gemm_out64<<<dim3(1024), 256, 0, stream>>>(
      Omh, Oml, w2h, w2l, b2, out);
}

// Round 14
// 219.562 us; speedup vs baseline: 1.0217x; 1.0180x over previous
//
#include <hip/hip_runtime.h>
#include <cstddef>

#define BATCH   2
#define SEQ     2048
#define DMODEL  1024
#define NH      16
#define HDIM    64
#define WIN     256
#define MTOT    4096

typedef __bf16 bf16;
typedef __attribute__((ext_vector_type(8)))  __bf16 bf16x8;
typedef __attribute__((ext_vector_type(4)))  float  f32x4;
typedef __attribute__((ext_vector_type(16))) float  f32x16;

#define GLOAD_LDS(gp, lp) __builtin_amdgcn_global_load_lds( \
    (const __attribute__((address_space(1))) void*)(gp),    \
    (__attribute__((address_space(3))) void*)(lp), 16, 0, 0)

__device__ __forceinline__ float fast_exp2(float x) {
#if __has_builtin(__builtin_amdgcn_exp2f)
  return __builtin_amdgcn_exp2f(x);
#else
  float r; asm("v_exp_f32 %0, %1" : "=v"(r) : "v"(x)); return r;
#endif
}

__device__ __forceinline__ unsigned int cvtpk_bf16(float lo, float hi) {
  unsigned int r;
  asm("v_cvt_pk_bf16_f32 %0, %1, %2" : "=v"(r) : "v"(lo), "v"(hi));
  return r;
}

// ---------------------------------------------------------------------------
// Merged pre-pass: split x, w1, w2 into bf16 hi/lo in one launch.
// ---------------------------------------------------------------------------
__global__ __launch_bounds__(256)
void cvt_all(const float* __restrict__ x, const float* __restrict__ w1,
             const float* __restrict__ w2, bf16* __restrict__ xh,
             bf16* __restrict__ xl, bf16* __restrict__ w1h,
             bf16* __restrict__ w1l, bf16* __restrict__ w2h,
             bf16* __restrict__ w2l) {
  const int bid = blockIdx.x;
  const float* s; bf16 *hp, *lp; int base;
  if (bid < 2048)      { s = x;  hp = xh;  lp = xl;  base = bid * 2048; }
  else if (bid < 3584) { s = w1; hp = w1h; lp = w1l; base = (bid - 2048) * 2048; }
  else                 { s = w2; hp = w2h; lp = w2l; base = (bid - 3584) * 2048; }
  const int i = base + threadIdx.x * 8;
  float4 a = *(const float4*)(s + i);
  float4 c = *(const float4*)(s + i + 4);
  const float f[8] = {a.x, a.y, a.z, a.w, c.x, c.y, c.z, c.w};
  bf16x8 vh, vl;
#pragma unroll
  for (int j = 0; j < 8; ++j) {
    bf16 hh = (bf16)f[j];
    vh[j] = hh;
    vl[j] = (bf16)(f[j] - (float)hh);
  }
  *(bf16x8*)(hp + i) = vh;
  *(bf16x8*)(lp + i) = vl;
}

// ---------------------------------------------------------------------------
// R21 = R19 revert (final form): fused QKV + V^T, single-buffer staging,
// 4 blocks/CU, XCD-local panels, bank-conflict-free LDS swizzle.
// R20 post-mortem: dbuf (56KB LDS) cut occupancy 4->2 blocks/CU; qkv
// 62.4->72.5us (m132 trade). The cross-block overlap at 4/CU (m114) was
// already hiding most of the drain — R19's form is the measured optimum
// of this structure (62.2-62.6us, conflicts 0, FETCH 45MB, ~670 TF).
//
// Frag-order K tile layout, 8KB per (b,h,kt): base ((b*16+h)*32+kt)*4096,
//   elem (key,d): ((key>>5)*4+(d>>4))*512 + (((d>>3)&1)*32+(key&31))*8 + (d&7)
// V tile elem (key,d): ((d>>5)*4+((key&63)>>4))*512
//                      + (((key>>3)&1)*32+(d&31))*8 + (key&7)
// ---------------------------------------------------------------------------
__global__ __launch_bounds__(256, 4)
void gemm_qkv_fused(const bf16* __restrict__ xh, const bf16* __restrict__ xl,
                    const bf16* __restrict__ w1h, const bf16* __restrict__ w1l,
                    const float* __restrict__ b1,
                    bf16* __restrict__ Qh, bf16* __restrict__ Ql,
                    bf16* __restrict__ Kt, bf16* __restrict__ Vt) {
  __shared__ bf16 sAh[128 * 32];
  __shared__ bf16 sAl[128 * 32];
  __shared__ bf16 sBh[128 * 32];
  __shared__ bf16 sBl[64 * 32];

  const int t = threadIdx.x, w = t >> 6, lane = t & 63;
  const int ln15 = lane & 15, quad = lane >> 4;
  const int drow = lane >> 2;
  // staging source col, pre-swizzled so linear LDS dest = swizzled layout:
  const int dkswz = (((lane & 3) ^ ((drow >> 1) & 3)) * 8);
  // reader col within row: swizzled 16B slot
  const int qswz = ((quad ^ ((ln15 >> 1) & 3)) * 8);
  const int bid = blockIdx.x;

  if (bid < 512) {
    // ---- Q: 128x64 tile, hi/lo cross (3 MFMA). XCD-local panel group.
    const int g = bid & 7, s = bid >> 3;       // g = XCD, s = 0..63
    const int bm = (g * 4 + (s >> 4)) * 128;   // 4 contiguous panels/XCD
    const int bn = (s & 15) * 64;

    f32x4 acc[2][4];
#pragma unroll
    for (int i = 0; i < 2; ++i)
#pragma unroll
      for (int j = 0; j < 4; ++j)
#pragma unroll
        for (int r = 0; r < 4; ++r) acc[i][j][r] = 0.f;

    for (int k0 = 0; k0 < DMODEL; k0 += 32) {
      __syncthreads();
#pragma unroll
      for (int half = 0; half < 2; ++half) {
        const int r = w * 32 + half * 16 + drow;
        const size_t goffA = (size_t)(bm + r) * DMODEL + k0 + dkswz;
        const int loff = (w * 32 + half * 16) * 32;
        GLOAD_LDS(xh + goffA, sAh + loff);
        GLOAD_LDS(xl + goffA, sAl + loff);
      }
      {
        const int r = w * 16 + drow;
        const size_t goffB = (size_t)(bn + r) * DMODEL + k0 + dkswz;
        const int loff = (w * 16) * 32;
        GLOAD_LDS(w1h + goffB, sBh + loff);
        GLOAD_LDS(w1l + goffB, sBl + loff);
      }
      __syncthreads();

      bf16x8 afh[2], afl[2], bfh[4], bfl[4];
#pragma unroll
      for (int mt = 0; mt < 2; ++mt) {
        const int off = (w * 32 + mt * 16 + ln15) * 32 + qswz;
        afh[mt] = *(const bf16x8*)&sAh[off];
        afl[mt] = *(const bf16x8*)&sAl[off];
      }
#pragma unroll
      for (int nt = 0; nt < 4; ++nt) {
        const int off = (nt * 16 + ln15) * 32 + qswz;
        bfh[nt] = *(const bf16x8*)&sBh[off];
        bfl[nt] = *(const bf16x8*)&sBl[off];
      }
#pragma unroll
      for (int mt = 0; mt < 2; ++mt)
#pragma unroll
        for (int nt = 0; nt < 4; ++nt) {
          acc[mt][nt] = __builtin_amdgcn_mfma_f32_16x16x32_bf16(afh[mt], bfh[nt], acc[mt][nt], 0, 0, 0);
          acc[mt][nt] = __builtin_amdgcn_mfma_f32_16x16x32_bf16(afh[mt], bfl[nt], acc[mt][nt], 0, 0, 0);
          acc[mt][nt] = __builtin_amdgcn_mfma_f32_16x16x32_bf16(afl[mt], bfh[nt], acc[mt][nt], 0, 0, 0);
        }
    }

    float bbcol[4];
#pragma unroll
    for (int nt = 0; nt < 4; ++nt) bbcol[nt] = b1[bn + nt * 16 + ln15];

#pragma unroll
    for (int mt = 0; mt < 2; ++mt)
#pragma unroll
      for (int r = 0; r < 4; ++r) {
        const size_t grow = (size_t)(bm + w * 32 + mt * 16 + quad * 4 + r);
#pragma unroll
        for (int nt = 0; nt < 4; ++nt) {
          const int col = bn + nt * 16 + ln15;
          const float v = acc[mt][nt][r] + bbcol[nt];
          const bf16 hh = (bf16)v;
          Qh[grow * 1024 + col] = hh;
          Ql[grow * 1024 + col] = (bf16)(v - (float)hh);
        }
      }
  } else if (bid < 768) {
    // ---- K: 128x128 hh-only -> Kt frag-order tiles. XCD-local panels.
    const int kid = bid - 512;
    const int g = kid & 7, s = kid >> 3;       // g = XCD, s = 0..31
    const int bm = (g * 4 + (s >> 3)) * 128;   // 4 contiguous panels/XCD
    const int bn = 1024 + (s & 7) * 128;
    const int wrow = (w & 1) * 64, wcol = (w >> 1) * 64;

    f32x4 acc[4][4];
#pragma unroll
    for (int i = 0; i < 4; ++i)
#pragma unroll
      for (int j = 0; j < 4; ++j)
#pragma unroll
        for (int r = 0; r < 4; ++r) acc[i][j][r] = 0.f;

    for (int k0 = 0; k0 < DMODEL; k0 += 32) {
      __syncthreads();
#pragma unroll
      for (int half = 0; half < 2; ++half) {
        const int r = w * 32 + half * 16 + drow;
        const int loff = (w * 32 + half * 16) * 32;
        GLOAD_LDS(xh + (size_t)(bm + r) * DMODEL + k0 + dkswz, sAh + loff);
        GLOAD_LDS(w1h + (size_t)(bn + r) * DMODEL + k0 + dkswz, sBh + loff);
      }
      __syncthreads();

      bf16x8 af[4], bf[4];
#pragma unroll
      for (int mt = 0; mt < 4; ++mt)
        af[mt] = *(const bf16x8*)&sAh[(wrow + mt * 16 + ln15) * 32 + qswz];
#pragma unroll
      for (int nt = 0; nt < 4; ++nt)
        bf[nt] = *(const bf16x8*)&sBh[(wcol + nt * 16 + ln15) * 32 + qswz];
#pragma unroll
      for (int mt = 0; mt < 4; ++mt)
#pragma unroll
        for (int nt = 0; nt < 4; ++nt)
          acc[mt][nt] = __builtin_amdgcn_mfma_f32_16x16x32_bf16(af[mt], bf[nt], acc[mt][nt], 0, 0, 0);
    }

    float bbcol[4];
#pragma unroll
    for (int nt = 0; nt < 4; ++nt) bbcol[nt] = b1[bn + wcol + nt * 16 + ln15];

#pragma unroll
    for (int mt = 0; mt < 4; ++mt)
#pragma unroll
      for (int r = 0; r < 4; ++r) {
        const size_t grow = (size_t)(bm + wrow + mt * 16 + quad * 4 + r);
        const int btok = (int)(grow >> 11), key = (int)(grow & 2047);
        const int kt = key >> 6, kw = key & 63;
#pragma unroll
        for (int nt = 0; nt < 4; ++nt) {
          const int col = bn + wcol + nt * 16 + ln15;
          const float v = acc[mt][nt][r] + bbcol[nt];
          const int hh2 = (col - 1024) >> 6, d = col & 63;
          const size_t addr = ((size_t)((btok * 16 + hh2) * 32 + kt) << 12)
                            + (((kw >> 5) * 4 + (d >> 4)) << 9)
                            + ((((d >> 3) & 1) << 5) + (kw & 31)) * 8 + (d & 7);
          Kt[addr] = (bf16)v;
        }
      }
  } else {
    // ---- V^T: A = w1h rows 2048..3071, B = xh, hh-only -> Vt tiles.
    const int vid = bid - 768;
    const int bm = (vid >> 5) * 128, bn = (vid & 31) * 128;
    const int wrow = (w & 1) * 64, wcol = (w >> 1) * 64;
    const bf16* Ah = w1h + 2048 * 1024;
    const float* bias = b1 + 2048;

    f32x4 acc[4][4];
#pragma unroll
    for (int i = 0; i < 4; ++i)
#pragma unroll
      for (int j = 0; j < 4; ++j)
#pragma unroll
        for (int r = 0; r < 4; ++r) acc[i][j][r] = 0.f;

    for (int k0 = 0; k0 < DMODEL; k0 += 32) {
      __syncthreads();
#pragma unroll
      for (int half = 0; half < 2; ++half) {
        const int r = w * 32 + half * 16 + drow;
        const int loff = (w * 32 + half * 16) * 32;
        GLOAD_LDS(Ah + (size_t)(bm + r) * DMODEL + k0 + dkswz, sAh + loff);
        GLOAD_LDS(xh + (size_t)(bn + r) * DMODEL + k0 + dkswz, sBh + loff);
      }
      __syncthreads();

      bf16x8 af[4], bf[4];
#pragma unroll
      for (int mt = 0; mt < 4; ++mt)
        af[mt] = *(const bf16x8*)&sAh[(wrow + mt * 16 + ln15) * 32 + qswz];
#pragma unroll
      for (int nt = 0; nt < 4; ++nt)
        bf[nt] = *(const bf16x8*)&sBh[(wcol + nt * 16 + ln15) * 32 + qswz];
#pragma unroll
      for (int mt = 0; mt < 4; ++mt)
#pragma unroll
        for (int nt = 0; nt < 4; ++nt)
          acc[mt][nt] = __builtin_amdgcn_mfma_f32_16x16x32_bf16(af[mt], bf[nt], acc[mt][nt], 0, 0, 0);
    }

#pragma unroll
    for (int mt = 0; mt < 4; ++mt)
#pragma unroll
      for (int r = 0; r < 4; ++r) {
        const size_t grow = (size_t)(bm + wrow + mt * 16 + quad * 4 + r);
        const float brow = bias[grow];
        const int hh2 = (int)(grow >> 6), d = (int)(grow & 63);
#pragma unroll
        for (int nt = 0; nt < 4; ++nt) {
          const int col = bn + wcol + nt * 16 + ln15;
          const float v = acc[mt][nt][r] + brow;
          const int btok = col >> 11, key = col & 2047;
          const int kt = key >> 6, kw = key & 63;
          const size_t addr = ((size_t)((btok * 16 + hh2) * 32 + kt) << 12)
                            + (((d >> 5) * 4 + (kw >> 4)) << 9)
                            + ((((kw >> 3) & 1) << 5) + (d & 31)) * 8 + (kw & 7);
          Vt[addr] = (bf16)v;
        }
      }
  }
}

// ---------------------------------------------------------------------------
// R19 out-proj (unchanged): 64x64 GEMM, BK=64, 3-bit slot swizzle,
// XCD-local 1D grid, plain stores.
// ---------------------------------------------------------------------------
__global__ __launch_bounds__(256)
void gemm_out64(const bf16* __restrict__ Ah, const bf16* __restrict__ Al,
                const bf16* __restrict__ Bh, const bf16* __restrict__ Bl,
                const float* __restrict__ bias, float* __restrict__ Cf) {
  __shared__ bf16 sAh[64 * 64];
  __shared__ bf16 sAl[64 * 64];
  __shared__ bf16 sBh[64 * 64];
  __shared__ bf16 sBl[64 * 64];

  const int t = threadIdx.x, w = t >> 6, lane = t & 63;
  const int ln15 = lane & 15, quad = lane >> 4;
  const int bid = blockIdx.x;
  const int g = bid & 7, s = bid >> 3;        // g = XCD, s = 0..127
  const int bm = (g * 8 + (s >> 4)) * 64;     // 8 contiguous panels/XCD
  const int bn = (s & 15) * 64;
  const int wrow = (w & 1) * 32, wcol = (w >> 1) * 32;
  const int drow8 = lane >> 3;                // 0..7 == row&7 of staged row
  const int dcol8 = (((lane & 7) ^ drow8) * 8);   // inverse-swizzled source

  f32x4 acc[2][2];
#pragma unroll
  for (int i = 0; i < 2; ++i)
#pragma unroll
    for (int j = 0; j < 2; ++j)
#pragma unroll
      for (int r = 0; r < 4; ++r) acc[i][j][r] = 0.f;

  for (int k0 = 0; k0 < DMODEL; k0 += 64) {
    __syncthreads();
#pragma unroll
    for (int p = 0; p < 2; ++p) {
      const int r = w * 16 + p * 8 + drow8;
      const size_t goffA = (size_t)(bm + r) * DMODEL + k0 + dcol8;
      const size_t goffB = (size_t)(bn + r) * DMODEL + k0 + dcol8;
      const int loff = (w * 16 + p * 8) * 64;
      GLOAD_LDS(Ah + goffA, sAh + loff);
      GLOAD_LDS(Al + goffA, sAl + loff);
      GLOAD_LDS(Bh + goffB, sBh + loff);
      GLOAD_LDS(Bl + goffB, sBl + loff);
    }
    __syncthreads();

#pragma unroll
    for (int ks = 0; ks < 2; ++ks) {
      bf16x8 afh[2], afl[2], bfh[2], bfl[2];
#pragma unroll
      for (int mt = 0; mt < 2; ++mt) {
        const int row = wrow + mt * 16 + ln15;
        const int off = row * 64 + (((ks * 4 + quad) ^ (row & 7)) * 8);
        afh[mt] = *(const bf16x8*)&sAh[off];
        afl[mt] = *(const bf16x8*)&sAl[off];
      }
#pragma unroll
      for (int nt = 0; nt < 2; ++nt) {
        const int row = wcol + nt * 16 + ln15;
        const int off = row * 64 + (((ks * 4 + quad) ^ (row & 7)) * 8);
        bfh[nt] = *(const bf16x8*)&sBh[off];
        bfl[nt] = *(const bf16x8*)&sBl[off];
      }
#pragma unroll
      for (int mt = 0; mt < 2; ++mt)
#pragma unroll
        for (int nt = 0; nt < 2; ++nt) {
          acc[mt][nt] = __builtin_amdgcn_mfma_f32_16x16x32_bf16(afh[mt], bfh[nt], acc[mt][nt], 0, 0, 0);
          acc[mt][nt] = __builtin_amdgcn_mfma_f32_16x16x32_bf16(afh[mt], bfl[nt], acc[mt][nt], 0, 0, 0);
          acc[mt][nt] = __builtin_amdgcn_mfma_f32_16x16x32_bf16(afl[mt], bfh[nt], acc[mt][nt], 0, 0, 0);
        }
    }
  }

  float bbcol[2];
#pragma unroll
  for (int nt = 0; nt < 2; ++nt) bbcol[nt] = bias[bn + wcol + nt * 16 + ln15];

#pragma unroll
  for (int mt = 0; mt < 2; ++mt)
#pragma unroll
    for (int r = 0; r < 4; ++r) {
      const size_t grow = (size_t)(bm + wrow + mt * 16 + quad * 4 + r);
#pragma unroll
      for (int nt = 0; nt < 2; ++nt) {
        const int col = bn + wcol + nt * 16 + ln15;
        Cf[grow * 1024 + col] = acc[mt][nt][r] + bbcol[nt];
      }
    }
}

// ---------------------------------------------------------------------------
// R14/R18 attention (unchanged — verified optimum for this structure).
// Swapped QK^T (mfma(K,Q)) -> P row lane-local; cvt_pk + permlane32_swap
// assemble PV A-fragments in-register; l = scalar f32. Zero LDS.
// ---------------------------------------------------------------------------
__global__ __launch_bounds__(64, 2)
void attn_mfma(const bf16* __restrict__ Qh, const bf16* __restrict__ Ql,
               const bf16* __restrict__ Kt, const bf16* __restrict__ Vt,
               bf16* __restrict__ Omh, bf16* __restrict__ Oml) {
  const int lane = threadIdx.x & 63;
  const int ln31 = lane & 31, half = lane >> 5;
  const int bid = blockIdx.x;
  const int j = bid & 31;
  const int bh = ((j & 7) << 2) | (j >> 3);    // bid%8 == bh>>2 -> XCD group
  const int c  = 63 - (bid >> 5);              // 32-row q chunk, long-first
  const int b = bh >> 4, h = bh & 15;
  const int i0w = c * 32;                      // this wave's first q row
  const int lim = i0w + WIN;                   // allowed: key <= q + WIN

  // ---- Q fragments: hi+lo combined, scaled by log2(e)/8, re-split ----
  bf16x8 qh[4], ql[4];
  {
    const size_t rowQ = (size_t)(b * SEQ + i0w + ln31);
#pragma unroll
    for (int ks = 0; ks < 4; ++ks) {
      bf16x8 vh = *(const bf16x8*)(Qh + rowQ * 1024 + h * 64 + ks * 16 + half * 8);
      bf16x8 vl = *(const bf16x8*)(Ql + rowQ * 1024 + h * 64 + ks * 16 + half * 8);
#pragma unroll
      for (int jj = 0; jj < 8; ++jj) {
        float f = ((float)vh[jj] + (float)vl[jj]) * 0.1803368801111204f;  // log2(e)/8
        bf16 hh = (bf16)f;
        qh[ks][jj] = hh;
        ql[ks][jj] = (bf16)(f - (float)hh);
      }
    }
  }

  f32x16 accO0, accO1;
#pragma unroll
  for (int r = 0; r < 16; ++r) { accO0[r] = 0.f; accO1[r] = 0.f; }
  float lsum = 0.f;

  // per-(b,h) tile bases; each tile is 4096 els, frag-slot ordered
  const bf16* KtBH = Kt + ((size_t)(b * 16 + h) << 17);
  const bf16* VtBH = Vt + ((size_t)(b * 16 + h) << 17);
  const int lane8 = lane * 8;

  const int nkt = min((i0w + 31 + WIN) / 64 + 1, SEQ / 64);

  for (int kt = 0; kt < nkt; ++kt) {
    const bf16* Kb = KtBH + ((size_t)kt << 12);
    const bf16* Vb = VtBH + ((size_t)kt << 12);

    // ---- load all 16 K/V fragments for this tile (1KB bursts, L2-hot).
    bf16x8 kf[8], vf[8];
#pragma unroll
    for (int s = 0; s < 8; ++s) {
      kf[s] = *(const bf16x8*)&Kb[(s << 9) + lane8];
      vf[s] = *(const bf16x8*)&Vb[(s << 9) + lane8];
    }

    // ---- S^T = K Q^T (swapped; Q split hh + hl) ----
    f32x16 S0, S1;
#pragma unroll
    for (int r = 0; r < 16; ++r) { S0[r] = 0.f; S1[r] = 0.f; }
    __builtin_amdgcn_s_setprio(1);
#pragma unroll
    for (int ks = 0; ks < 4; ++ks) {
      S0 = __builtin_amdgcn_mfma_f32_32x32x16_bf16(kf[ks], qh[ks], S0, 0, 0, 0);
      S0 = __builtin_amdgcn_mfma_f32_32x32x16_bf16(kf[ks], ql[ks], S0, 0, 0, 0);
      S1 = __builtin_amdgcn_mfma_f32_32x32x16_bf16(kf[4 + ks], qh[ks], S1, 0, 0, 0);
      S1 = __builtin_amdgcn_mfma_f32_32x32x16_bf16(kf[4 + ks], ql[ks], S1, 0, 0, 0);
    }
    __builtin_amdgcn_s_setprio(0);

    // ---- in-register softmax: p = exp2(s), mask, pack to PV fragments ----
    const int j0 = kt * 64;
    bf16x8 pa[4];
#pragma unroll
    for (int cc = 0; cc < 2; ++cc) {
      f32x16& S = cc ? S1 : S0;
      const int base = j0 + cc * 32 - lim;     // zero if kr + base > ln31
      const bool may = (base + 31 > 0);
#pragma unroll
      for (int r = 0; r < 16; ++r) {
        const int kr = (r & 3) + 8 * (r >> 2) + 4 * half;  // key row in block
        float pv = fast_exp2(S[r]);
        if (may && (kr + base > ln31)) pv = 0.f;
        S[r] = pv;
        lsum += pv;
      }
      unsigned int W0[4], W1[4];
#pragma unroll
      for (int g = 0; g < 4; ++g) {
        W0[g] = cvtpk_bf16(S[4 * g + 0], S[4 * g + 1]);
        W1[g] = cvtpk_bf16(S[4 * g + 2], S[4 * g + 3]);
      }
#pragma unroll
      for (int f = 0; f < 2; ++f) {
        auto s0 = __builtin_amdgcn_permlane32_swap(W0[2 * f], W0[2 * f + 1], false, false);
        auto s1 = __builtin_amdgcn_permlane32_swap(W1[2 * f], W1[2 * f + 1], false, false);
        union { unsigned int w[4]; bf16x8 v; } u;
        u.w[0] = (unsigned int)s0[0];
        u.w[1] = (unsigned int)s1[0];
        u.w[2] = (unsigned int)s0[1];
        u.w[3] = (unsigned int)s1[1];
        pa[cc * 2 + f] = u.v;
      }
    }

    // ---- O += P V (A = in-register P fragments; no LDS, no barrier) ----
    __builtin_amdgcn_s_setprio(1);
#pragma unroll
    for (int ks = 0; ks < 4; ++ks) {
      accO0 = __builtin_amdgcn_mfma_f32_32x32x16_bf16(pa[ks], vf[ks], accO0, 0, 0, 0);
      accO1 = __builtin_amdgcn_mfma_f32_32x32x16_bf16(pa[ks], vf[4 + ks], accO1, 0, 0, 0);
    }
    __builtin_amdgcn_s_setprio(0);
  }

  // ---- epilogue: combine l across halves, O /= l, write Om hi/lo ----
  lsum += __shfl_xor(lsum, 32, 64);            // lane q + partner -> full l[q=ln31]
#pragma unroll
  for (int r = 0; r < 16; ++r) {
    const int rl = (r & 3) + 8 * (r >> 2) + 4 * half;
    const float lv = __shfl(lsum, rl, 64);     // l for O row rl
    const float inv = 1.0f / lv;
    const size_t grow = (size_t)(b * SEQ + i0w + rl);
    const int col0 = h * 64 + ln31;
    const float v0 = accO0[r] * inv;
    const float v1 = accO1[r] * inv;
    const bf16 h0 = (bf16)v0, h1 = (bf16)v1;
    Omh[grow * DMODEL + col0]      = h0;
    Oml[grow * DMODEL + col0]      = (bf16)(v0 - (float)h0);
    Omh[grow * DMODEL + col0 + 32] = h1;
    Oml[grow * DMODEL + col0 + 32] = (bf16)(v1 - (float)h1);
  }
}

// ---------------------------------------------------------------------------
extern "C" void kernel_launch(void* const* d_in, const int* in_sizes, int n_in,
                              void* d_out, int out_size, void* d_ws, size_t ws_size,
                              hipStream_t stream) {
  const float* x  = (const float*)d_in[0];
  const float* w1 = (const float*)d_in[1];
  const float* b1 = (const float*)d_in[2];
  const float* w2 = (const float*)d_in[3];
  const float* b2 = (const float*)d_in[4];
  float* out = (float*)d_out;

  char* ws = (char*)d_ws;
  bf16* Qh   = (bf16*)(ws + 0);          // [4096][1024]
  bf16* Ql   = (bf16*)(ws + 8388608);    // [4096][1024]
  bf16* Kt   = (bf16*)(ws + 16777216);   // frag-order tiles, 8 MB
  bf16* Vt   = (bf16*)(ws + 25165824);   // frag-order tiles, 8 MB
  bf16* xh   = (bf16*)(ws + 33554432);   // [4096][1024]
  bf16* xl   = (bf16*)(ws + 41943040);
  bf16* w1h  = (bf16*)(ws + 50331648);   // [3072][1024]
  bf16* w1l  = (bf16*)(ws + 56623104);
  bf16* w2h  = (bf16*)(ws + 62914560);   // [1024][1024]
  bf16* w2l  = (bf16*)(ws + 65011712);
  bf16* Omh  = xh;                       // reuse (x dead after fused gemm)
  bf16* Oml  = xl;

  cvt_all<<<dim3(4096), 256, 0, stream>>>(x, w1, w2, xh, xl, w1h, w1l, w2h, w2l);

  // fused: Q 128x64 (0..511) + K 128x128 (512..767) + V^T (768..1023),
  // XCD-local panels + bank-conflict-free LDS swizzle (R19 form)
  gemm_qkv_fused<<<dim3(1024), 256, 0, stream>>>(
      xh, xl, w1h, w1l, b1, Qh, Ql, Kt, Vt);

  // 1-wave in-register-softmax attention (R14 exact)
  attn_mfma<<<dim3(2048), 64, 0, stream>>>(Qh, Ql, Kt, Vt, Omh, Oml);

  // out = Om @ w2^T + b2 (fp32), 64x64 tiles, BK=64, 3-bit swizzle
  gemm_out64<<<dim3(1024), 256, 0, stream>>>(
      Omh, Oml, w2h, w2l, b2, out);
}